// Round 1
// baseline (237.562 us; speedup 1.0000x reference)
//
#include <hip/hip_runtime.h>
#include <math.h>

#define EPS 1e-7f

constexpr int B = 16, L = 1024, D = 256, P = 20;
constexpr int LD = L * D;     // 262144
constexpr int DD = D * D;     // 65536

// ---------------------------------------------------------------------------
// ws layout (floats):
//   n1    : [B*L]     @ 0        (16384)
//   invn2 : [B*L]     @ 16384    (16384)
//   t     : [B*D]     @ 32768    (4096)    -- zeroed, atomic-accumulated
//   G     : [B*D*D]   @ 36864    (1048576) -- zeroed, atomic-accumulated
//   mav   : [B*L*D]   @ 1085440  (4194304)
// total 5279744 floats = 21.1 MB
// ---------------------------------------------------------------------------

// K1: per-row L2 norms. n1 stored plain, n2 stored as reciprocal.
// One wave per 256-float row, 4 rows/block.
__global__ __launch_bounds__(256) void k_norms(const float* __restrict__ s1,
                                               const float* __restrict__ s2,
                                               float* __restrict__ n1,
                                               float* __restrict__ invn2) {
    int tid  = threadIdx.x;
    int lane = tid & 63, w = tid >> 6;
    int row  = blockIdx.x * 4 + w;            // 0..32767
    int r    = (row < B * L) ? row : row - B * L;
    const float* src = (row < B * L) ? s1 : s2;
    float4 v = *(const float4*)(src + (size_t)r * D + lane * 4);
    float s = v.x * v.x + v.y * v.y + v.z * v.z + v.w * v.w;
#pragma unroll
    for (int o = 32; o; o >>= 1) s += __shfl_down(s, o);
    if (lane == 0) {
        float n = sqrtf(fmaxf(s, EPS));
        if (row < B * L) n1[r] = n;
        else             invn2[r] = 1.0f / n;
    }
}

// K2: t[b,d] = sum_m s2[b,m,d] * invn2[b,m].  Grid: 16 b x 8 m-chunks.
__global__ __launch_bounds__(256) void k_t(const float* __restrict__ s2,
                                           const float* __restrict__ invn2,
                                           float* __restrict__ t) {
    int b  = blockIdx.x >> 3;
    int mc = blockIdx.x & 7;                  // 128 m per chunk
    int d  = threadIdx.x;
    const float* sp = s2 + (size_t)b * LD + (size_t)mc * 128 * D + d;
    const float* wp = invn2 + b * L + mc * 128;
    float acc = 0.f;
#pragma unroll 4
    for (int m = 0; m < 128; ++m) acc += sp[(size_t)m * D] * wp[m];
    atomicAdd(&t[b * D + d], acc);
}

// K3: G[b] += S2_chunk^T diag(invn2) S2_chunk.  128x128 tile, 8x8/thread,
// K(m)-split x4 with atomicAdd into G.  Grid: 16 b x (2 ti x 2 tj x 4 kc).
__global__ __launch_bounds__(256) void k_gram(const float* __restrict__ s2,
                                              const float* __restrict__ invn2,
                                              float* __restrict__ G) {
    __shared__ float As[16][132];
    __shared__ float Bs[16][132];
    int tid = threadIdx.x;
    int b   = blockIdx.x >> 4;
    int rem = blockIdx.x & 15;
    int kc  = rem & 3;
    int tj  = (rem >> 2) & 1;
    int ti  = (rem >> 3) & 1;
    int tx  = tid & 15, ty = tid >> 4;
    int m0  = kc * 256;

    float acc[8][8];
#pragma unroll
    for (int i = 0; i < 8; ++i)
#pragma unroll
        for (int j = 0; j < 8; ++j) acc[i][j] = 0.f;

    for (int mc = 0; mc < 16; ++mc) {
        int mbase = m0 + mc * 16;
        __syncthreads();
        {
            int c = tid & 31, r0 = tid >> 5;   // r0 0..7
#pragma unroll
            for (int p2 = 0; p2 < 2; ++p2) {
                int r = r0 + p2 * 8;
                float w = invn2[b * L + mbase + r];
                const float* base = s2 + (size_t)b * LD + (size_t)(mbase + r) * D;
                float4 va = *(const float4*)(base + ti * 128 + c * 4);
                float4 vb = *(const float4*)(base + tj * 128 + c * 4);
                float4 sa; sa.x = va.x * w; sa.y = va.y * w; sa.z = va.z * w; sa.w = va.w * w;
                *(float4*)&As[r][c * 4] = sa;
                *(float4*)&Bs[r][c * 4] = vb;
            }
        }
        __syncthreads();
#pragma unroll
        for (int k = 0; k < 16; ++k) {
            float4 a0 = *(const float4*)&As[k][ty * 4];
            float4 a1 = *(const float4*)&As[k][64 + ty * 4];
            float4 b0 = *(const float4*)&Bs[k][tx * 4];
            float4 b1 = *(const float4*)&Bs[k][64 + tx * 4];
            float a[8] = {a0.x, a0.y, a0.z, a0.w, a1.x, a1.y, a1.z, a1.w};
            float bb[8] = {b0.x, b0.y, b0.z, b0.w, b1.x, b1.y, b1.z, b1.w};
#pragma unroll
            for (int i = 0; i < 8; ++i)
#pragma unroll
                for (int j = 0; j < 8; ++j) acc[i][j] += a[i] * bb[j];
        }
    }
#pragma unroll
    for (int i = 0; i < 8; ++i) {
        int row = (i < 4) ? (ty * 4 + i) : (64 + ty * 4 + i - 4);
#pragma unroll
        for (int j = 0; j < 8; ++j) {
            int col = (j < 4) ? (tx * 4 + j) : (64 + tx * 4 + j - 4);
            atomicAdd(&G[(size_t)b * DD + (size_t)(ti * 128 + row) * D + tj * 128 + col],
                      acc[i][j]);
        }
    }
}

// K4: u = s1 @ G (per batch), fused U = s1 . t accumulation, epilogue writes
// mav = u / (U + EPS*n1).  128x128 tiles, 8x8/thread.  Grid: 16 b x 8 lt x 2 nt.
__global__ __launch_bounds__(256) void k_mav(const float* __restrict__ s1,
                                             const float* __restrict__ G,
                                             const float* __restrict__ t,
                                             const float* __restrict__ n1,
                                             float* __restrict__ mav) {
    __shared__ float As[16][132];   // transposed s1 chunk: As[k][l]
    __shared__ float Bs[16][132];   // G chunk: Bs[k][n]
    __shared__ float ts[16];
    int tid = threadIdx.x;
    int b   = blockIdx.x >> 4;
    int rem = blockIdx.x & 15;
    int lt  = rem >> 1, nt = rem & 1;
    int l0  = lt * 128, n0 = nt * 128;
    int tx  = tid & 15, ty = tid >> 4;

    float acc[8][8];
    float Ua[8];
#pragma unroll
    for (int i = 0; i < 8; ++i) {
        Ua[i] = 0.f;
#pragma unroll
        for (int j = 0; j < 8; ++j) acc[i][j] = 0.f;
    }

    for (int kc = 0; kc < 16; ++kc) {
        __syncthreads();
        {
            // stage A (transpose): s1[l0+l][kc*16 + c4*4 .. +3] -> As[k][l]
            int c4 = tid & 3, lrow = tid >> 2;   // lrow 0..63
#pragma unroll
            for (int p2 = 0; p2 < 2; ++p2) {
                int l = lrow + p2 * 64;
                float4 v = *(const float4*)(s1 + (size_t)b * LD + (size_t)(l0 + l) * D +
                                            kc * 16 + c4 * 4);
                As[c4 * 4 + 0][l] = v.x;
                As[c4 * 4 + 1][l] = v.y;
                As[c4 * 4 + 2][l] = v.z;
                As[c4 * 4 + 3][l] = v.w;
            }
            // stage B: G[kc*16+r][n0 + c*4]
            int c = tid & 31, r0 = tid >> 5;
#pragma unroll
            for (int p2 = 0; p2 < 2; ++p2) {
                int r = r0 + p2 * 8;
                float4 v = *(const float4*)(G + (size_t)b * DD + (size_t)(kc * 16 + r) * D +
                                            n0 + c * 4);
                *(float4*)&Bs[r][c * 4] = v;
            }
            if (tid < 16) ts[tid] = t[b * D + kc * 16 + tid];
        }
        __syncthreads();
#pragma unroll
        for (int k = 0; k < 16; ++k) {
            float4 a0 = *(const float4*)&As[k][ty * 4];
            float4 a1 = *(const float4*)&As[k][64 + ty * 4];
            float4 b0 = *(const float4*)&Bs[k][tx * 4];
            float4 b1 = *(const float4*)&Bs[k][64 + tx * 4];
            float tk = ts[k];
            float a[8] = {a0.x, a0.y, a0.z, a0.w, a1.x, a1.y, a1.z, a1.w};
            float bb[8] = {b0.x, b0.y, b0.z, b0.w, b1.x, b1.y, b1.z, b1.w};
#pragma unroll
            for (int i = 0; i < 8; ++i) {
                Ua[i] += a[i] * tk;
#pragma unroll
                for (int j = 0; j < 8; ++j) acc[i][j] += a[i] * bb[j];
            }
        }
    }
#pragma unroll
    for (int i = 0; i < 8; ++i) {
        int row = (i < 4) ? (ty * 4 + i) : (64 + ty * 4 + i - 4);
        int l   = l0 + row;
        float n1v = n1[b * L + l];
        float inv = 1.0f / (Ua[i] + EPS * n1v);
        float4 o0, o1;
        o0.x = acc[i][0] * inv; o0.y = acc[i][1] * inv;
        o0.z = acc[i][2] * inv; o0.w = acc[i][3] * inv;
        o1.x = acc[i][4] * inv; o1.y = acc[i][5] * inv;
        o1.z = acc[i][6] * inv; o1.w = acc[i][7] * inv;
        float* dst = mav + (size_t)(b * L + l) * D;
        *(float4*)(dst + n0 + tx * 4)      = o0;
        *(float4*)(dst + n0 + 64 + tx * 4) = o1;
    }
}

// K5: out[b,l,p] = num / nv1 / nv2 over k2 = kernel^2.  One wave per row,
// lane = (psub 0..3) x (dg 0..15); dg owns d in {64j + dg*4 + 0..3}.
__global__ __launch_bounds__(256) void k_out(const float* __restrict__ s1,
                                             const float* __restrict__ mav,
                                             const float* __restrict__ kern,
                                             float* __restrict__ out) {
    __shared__ float k2s[P * D];   // 20 KB
    int tid = threadIdx.x;
#pragma unroll
    for (int p = 0; p < P; ++p) {
        float v = kern[p * D + tid];
        k2s[p * D + tid] = v * v;
    }
    __syncthreads();

    int w = tid >> 6, lane = tid & 63;
    int row = blockIdx.x * 4 + w;             // 0..16383
    int dg = lane & 15, ps = lane >> 4;

    const float* s1p = s1 + (size_t)row * D + dg * 4;
    const float* mvp = mav + (size_t)row * D + dg * 4;
    float4 sm[4], ss[4], mm[4];
#pragma unroll
    for (int j = 0; j < 4; ++j) {
        float4 sv = *(const float4*)(s1p + j * 64);
        float4 mv = *(const float4*)(mvp + j * 64);
        sm[j].x = sv.x * mv.x; sm[j].y = sv.y * mv.y; sm[j].z = sv.z * mv.z; sm[j].w = sv.w * mv.w;
        ss[j].x = sv.x * sv.x; ss[j].y = sv.y * sv.y; ss[j].z = sv.z * sv.z; ss[j].w = sv.w * sv.w;
        mm[j].x = mv.x * mv.x; mm[j].y = mv.y * mv.y; mm[j].z = mv.z * mv.z; mm[j].w = mv.w * mv.w;
    }
#pragma unroll
    for (int tI = 0; tI < 5; ++tI) {
        int p = ps + tI * 4;                  // 0..19, always valid
        float na = 0.f, nb = 0.f, nc = 0.f;
#pragma unroll
        for (int j = 0; j < 4; ++j) {
            float4 kv = *(const float4*)&k2s[p * D + j * 64 + dg * 4];
            na += sm[j].x * kv.x + sm[j].y * kv.y + sm[j].z * kv.z + sm[j].w * kv.w;
            nb += ss[j].x * kv.x + ss[j].y * kv.y + ss[j].z * kv.z + ss[j].w * kv.w;
            nc += mm[j].x * kv.x + mm[j].y * kv.y + mm[j].z * kv.z + mm[j].w * kv.w;
        }
#pragma unroll
        for (int o = 8; o; o >>= 1) {
            na += __shfl_down(na, o, 16);
            nb += __shfl_down(nb, o, 16);
            nc += __shfl_down(nc, o, 16);
        }
        if (dg == 0) {
            float d1 = sqrtf(fmaxf(nb, EPS));
            float d2 = sqrtf(fmaxf(nc, EPS));
            out[row * P + p] = na / d1 / d2;
        }
    }
}

extern "C" void kernel_launch(void* const* d_in, const int* in_sizes, int n_in,
                              void* d_out, int out_size, void* d_ws, size_t ws_size,
                              hipStream_t stream) {
    const float* s1   = (const float*)d_in[0];
    const float* s2   = (const float*)d_in[1];
    const float* kern = (const float*)d_in[2];
    float* out = (float*)d_out;
    float* ws  = (float*)d_ws;

    float* n1    = ws;
    float* invn2 = ws + 16384;
    float* t     = ws + 32768;
    float* G     = ws + 36864;
    float* mav   = ws + 1085440;

    // zero t (4096) + G (1048576) — contiguous region
    hipMemsetAsync(t, 0, (size_t)(4096 + 1048576) * sizeof(float), stream);

    k_norms<<<8192, 256, 0, stream>>>(s1, s2, n1, invn2);
    k_t<<<128, 256, 0, stream>>>(s2, invn2, t);
    k_gram<<<256, 256, 0, stream>>>(s2, invn2, G);
    k_mav<<<256, 256, 0, stream>>>(s1, G, t, n1, mav);
    k_out<<<4096, 256, 0, stream>>>(s1, mav, kern, out);
}